// Round 8
// baseline (169.269 us; speedup 1.0000x reference)
//
#include <hip/hip_runtime.h>
#include <cstdint>
#include <cstddef>

// Problem shape (fixed by setup_inputs): hidden [4,2048,2048] -> M=8192, K=2048, N=2048
#define MDIM 8192
#define NDIM 2048
#define KDIM 2048

constexpr int BM = 256, BN = 256, BK = 64;   // dbuf: 2 x (16KB A + 16KB B) = 64 KB LDS

typedef int v4i __attribute__((ext_vector_type(4)));

__device__ __forceinline__ void async_ld16(const void* g, void* l) {
    __builtin_amdgcn_global_load_lds(
        (const __attribute__((address_space(1))) int*)g,
        (__attribute__((address_space(3))) int*)l,
        16, 0, 0);
}

// ---------- fused quantize: x fp32 -> int8 (packed u32)  +  W fp32 [K][N] -> int8 [N][K] ----------
__device__ __forceinline__ uint32_t q8(float x, float inv) {
    float q = fminf(fmaxf(rintf(x * inv), -127.f), 127.f);
    return (uint32_t)((int)q) & 0xffu;
}

// W-part first (blocks 0..1023), then x-part: 4096 blocks x 256 threads x 4 chunked float4
#define WBLOCKS ((KDIM / 64) * (NDIM / 64))       // 1024
#define XCHUNK (MDIM * KDIM / 4 / 4)              // float4s per chunk = 1048576
#define XBLOCKS (XCHUNK / 256)                    // 4096 blocks

__global__ void quant_kernel(const float4* __restrict__ x, uint32_t* __restrict__ xq,
                             const float* __restrict__ scale_p,
                             const float* __restrict__ w, uint32_t* __restrict__ wt) {
    __shared__ uint32_t t[64][17];
    const int tid = threadIdx.x;

    if (blockIdx.x >= WBLOCKS) {
        // ---- x quant: thread handles 4 float4s at chunk stride (all accesses coalesced) ----
        int i = (blockIdx.x - WBLOCKS) * 256 + tid;
        float inv = 1.0f / fmaxf(scale_p[0], 1e-8f);
#pragma unroll
        for (int k = 0; k < 4; ++k) {
            float4 v = x[i + k * XCHUNK];
            xq[i + k * XCHUNK] =
                q8(v.x, inv) | (q8(v.y, inv) << 8) | (q8(v.z, inv) << 16) | (q8(v.w, inv) << 24);
        }
        return;
    }

    // ---- W quant + transpose: 64x64 tile per block ----
    const int bid = blockIdx.x;                    // 0..1023
    const int k0 = (bid >> 5) * 64;                // KDIM/64 = 32
    const int n0 = (bid & 31) * 64;                // NDIM/64 = 32
    const int rr  = tid >> 4;                      // 0..15
    const int c4  = (tid & 15) * 4;                // 0..60
#pragma unroll
    for (int p = 0; p < 4; ++p) {
        int r = rr + p * 16;
        float4 v = *(const float4*)&w[(size_t)(k0 + r) * NDIM + n0 + c4];
        uint32_t pk = (uint32_t)((int)rintf(v.x) & 0xff)
                    | ((uint32_t)((int)rintf(v.y) & 0xff) << 8)
                    | ((uint32_t)((int)rintf(v.z) & 0xff) << 16)
                    | ((uint32_t)((int)rintf(v.w) & 0xff) << 24);
        t[r][c4 >> 2] = pk;
    }
    __syncthreads();
    // read side: thread owns column c = rr+p*16, rows c4..c4+3 -> one uint32 out
#pragma unroll
    for (int p = 0; p < 4; ++p) {
        int c = rr + p * 16;
        uint32_t o = 0;
#pragma unroll
        for (int j = 0; j < 4; ++j) {
            uint32_t b = (t[c4 + j][c >> 2] >> ((c & 3) * 8)) & 0xffu;
            o |= b << (j * 8);
        }
        wt[((size_t)(n0 + c) * KDIM + k0 + c4) >> 2] = o;
    }
}

// ---------- i8 GEMM: C = A * Bt^T + bias; 256^2 tile, 1024 thr (16 waves), R0 sync ----------
// Ratio endpoint: 256 i8-ops per staged byte (128^2: 128, 128x256: 171). Residency held at
// the proven 16 waves/CU: launch_bounds(1024,4) -> 128-reg cap (unified VGPR+AGPR file;
// acc 64 AGPR + ~60 VGPR fits — R6's (512,6)=85-reg cap spilled 1 GB, never again).
// LDS row = 64B = 4 x 16B chunks; chunk c of row r at slot c ^ ((r>>1)&3): all wave-row
// bases are multiples of 16 so the XOR term depends only on lr; verified 0 conflicts.
__global__ __launch_bounds__(1024, 4)
void gemm_i8_kernel(const int8_t* __restrict__ A,   // [M][K] int8
                    const int8_t* __restrict__ Bt,  // [N][K] int8
                    const float* __restrict__ bias, // [N]
                    float* __restrict__ C) {        // [M][N] fp32
    __shared__ alignas(16) int8_t lA[2][BM * BK];   // 2 x 16 KB
    __shared__ alignas(16) int8_t lB[2][BN * BK];   // 2 x 16 KB

    const int tid  = threadIdx.x;
    const int lane = tid & 63;
    const int wave = tid >> 6;           // 0..15
    const int wm   = wave & 3;           // M-quarter: 64 rows
    const int wn   = wave >> 2;          // N-quarter: 64 cols

    // XCD-aware bijective swizzle: 256 blocks -> 32 per XCD = 4 m-panels x 8 n-panels
    const int bidlin = blockIdx.y * gridDim.x + blockIdx.x;   // 0..255
    const int xcd    = bidlin & 7;
    const int idx    = bidlin >> 3;                            // 0..31
    const int m0     = (xcd * 4 + (idx >> 3)) * BM;            // 32 m-panels
    const int n0     = (idx & 7) * BN;                         // 8 n-panels

    // staging: wave covers 16 rows of A and 16 rows of B; 2 async loads / thread / tile
    const int srow = lane >> 2;                       // 0..15
    const int schk = (lane & 3) ^ ((srow >> 1) & 3);  // swizzled source chunk
    const int8_t* gA = A  + (size_t)(m0 + wave * 16 + srow) * KDIM + schk * 16;
    const int8_t* gB = Bt + (size_t)(n0 + wave * 16 + srow) * KDIM + schk * 16;
    const int lwo = wave * 1024;

    // fragments: lane reads row (.. + lr), global chunk quad -> LDS chunk quad^((lr>>1)&3)
    const int quad = lane >> 4;
    const int lr   = lane & 15;
    const int fchk = (quad ^ ((lr >> 1) & 3)) * 16;
    const int aoff = (wm * 64 + lr) * BK + fchk;
    const int boff = (wn * 64 + lr) * BK + fchk;

    v4i acc[4][4];
#pragma unroll
    for (int i = 0; i < 4; ++i)
#pragma unroll
        for (int j = 0; j < 4; ++j)
            acc[i][j] = (v4i){0, 0, 0, 0};

#define STAGE(buf, kof)                                                        \
    do {                                                                       \
        async_ld16(gA + (kof), &lA[buf][lwo]);                                 \
        async_ld16(gB + (kof), &lB[buf][lwo]);                                 \
    } while (0)

#define COMPUTE(buf)                                                           \
    do {                                                                       \
        v4i af[4], bf[4];                                                      \
        _Pragma("unroll")                                                      \
        for (int i = 0; i < 4; ++i)                                            \
            af[i] = *(const v4i*)&lA[buf][aoff + i * 1024];                    \
        _Pragma("unroll")                                                      \
        for (int j = 0; j < 4; ++j)                                            \
            bf[j] = *(const v4i*)&lB[buf][boff + j * 1024];                    \
        _Pragma("unroll")                                                      \
        for (int i = 0; i < 4; ++i)                                            \
            _Pragma("unroll")                                                  \
            for (int j = 0; j < 4; ++j)                                        \
                acc[i][j] = __builtin_amdgcn_mfma_i32_16x16x64_i8(             \
                    af[i], bf[j], acc[i][j], 0, 0, 0);                         \
    } while (0)

    STAGE(0, 0);
    int kof = BK;
    for (int it = 0; it < KDIM / BK - 1; ++it) {
        __syncthreads();                 // drains vmcnt: tile `it` visible; buf (it+1)&1 free
        STAGE((it + 1) & 1, kof);        // prefetch next tile (flies during compute)
        kof += BK;
        COMPUTE(it & 1);
    }
    __syncthreads();
    COMPUTE((KDIM / BK - 1) & 1);

    // epilogue: C/D layout col = lane&15, row = quad*4 + reg (verified, dtype-indep)
    const int crow = m0 + wm * 64 + quad * 4;
    const int ccol = n0 + wn * 64 + lr;
    float bj[4];
#pragma unroll
    for (int j = 0; j < 4; ++j) bj[j] = bias[ccol + j * 16];
#pragma unroll
    for (int i = 0; i < 4; ++i)
#pragma unroll
        for (int j = 0; j < 4; ++j)
#pragma unroll
            for (int r = 0; r < 4; ++r)
                C[(size_t)(crow + i * 16 + r) * NDIM + (ccol + j * 16)] = (float)acc[i][j][r] + bj[j];
}

extern "C" void kernel_launch(void* const* d_in, const int* in_sizes, int n_in,
                              void* d_out, int out_size, void* d_ws, size_t ws_size,
                              hipStream_t stream) {
    const float* x    = (const float*)d_in[0];   // [8192, 2048] fp32
    const float* w    = (const float*)d_in[1];   // [2048, 2048] fp32 (integer-valued)
    const float* xs   = (const float*)d_in[2];   // scalar
    const float* bias = (const float*)d_in[3];   // [2048]
    float* out = (float*)d_out;                  // [8192, 2048] fp32

    int8_t* xq = (int8_t*)d_ws;                          // 16 MB
    int8_t* wt = xq + (size_t)MDIM * KDIM;               //  4 MB

    quant_kernel<<<WBLOCKS + XBLOCKS, 256, 0, stream>>>(
        (const float4*)x, (uint32_t*)xq, xs, w, (uint32_t*)wt);
    gemm_i8_kernel<<<dim3(NDIM / BN, MDIM / BM), 1024, 0, stream>>>(xq, wt, bias, out);
}

// Round 9
// 163.407 us; speedup vs baseline: 1.0359x; 1.0359x over previous
//
#include <hip/hip_runtime.h>
#include <cstdint>
#include <cstddef>

// Problem shape (fixed by setup_inputs): hidden [4,2048,2048] -> M=8192, K=2048, N=2048
#define MDIM 8192
#define NDIM 2048
#define KDIM 2048

constexpr int BM = 128, BN = 256, BK = 64;   // dbuf: 2 x (8KB A + 16KB B) = 48 KB -> 2 blocks/CU

typedef int v4i __attribute__((ext_vector_type(4)));

__device__ __forceinline__ void async_ld16(const void* g, void* l) {
    __builtin_amdgcn_global_load_lds(
        (const __attribute__((address_space(1))) int*)g,
        (__attribute__((address_space(3))) int*)l,
        16, 0, 0);
}

// ---------- fused quantize: x fp32 -> int8 (packed u32)  +  W fp32 [K][N] -> int8 [N][K] ----------
__device__ __forceinline__ uint32_t q8(float x, float inv) {
    float q = fminf(fmaxf(rintf(x * inv), -127.f), 127.f);
    return (uint32_t)((int)q) & 0xffu;
}

// W-part first (blocks 0..1023), then x-part: 4096 blocks x 256 threads x 4 chunked float4
#define WBLOCKS ((KDIM / 64) * (NDIM / 64))       // 1024
#define XCHUNK (MDIM * KDIM / 4 / 4)              // float4s per chunk = 1048576
#define XBLOCKS (XCHUNK / 256)                    // 4096 blocks

__global__ void quant_kernel(const float4* __restrict__ x, uint32_t* __restrict__ xq,
                             const float* __restrict__ scale_p,
                             const float* __restrict__ w, uint32_t* __restrict__ wt) {
    __shared__ uint32_t t[64][17];
    const int tid = threadIdx.x;

    if (blockIdx.x >= WBLOCKS) {
        // ---- x quant: thread handles 4 float4s at chunk stride (all accesses coalesced) ----
        int i = (blockIdx.x - WBLOCKS) * 256 + tid;
        float inv = 1.0f / fmaxf(scale_p[0], 1e-8f);
#pragma unroll
        for (int k = 0; k < 4; ++k) {
            float4 v = x[i + k * XCHUNK];
            xq[i + k * XCHUNK] =
                q8(v.x, inv) | (q8(v.y, inv) << 8) | (q8(v.z, inv) << 16) | (q8(v.w, inv) << 24);
        }
        return;
    }

    // ---- W quant + transpose: 64x64 tile per block ----
    const int bid = blockIdx.x;                    // 0..1023
    const int k0 = (bid >> 5) * 64;                // KDIM/64 = 32
    const int n0 = (bid & 31) * 64;                // NDIM/64 = 32
    const int rr  = tid >> 4;                      // 0..15
    const int c4  = (tid & 15) * 4;                // 0..60
#pragma unroll
    for (int p = 0; p < 4; ++p) {
        int r = rr + p * 16;
        float4 v = *(const float4*)&w[(size_t)(k0 + r) * NDIM + n0 + c4];
        uint32_t pk = (uint32_t)((int)rintf(v.x) & 0xff)
                    | ((uint32_t)((int)rintf(v.y) & 0xff) << 8)
                    | ((uint32_t)((int)rintf(v.z) & 0xff) << 16)
                    | ((uint32_t)((int)rintf(v.w) & 0xff) << 24);
        t[r][c4 >> 2] = pk;
    }
    __syncthreads();
    // read side: thread owns column c = rr+p*16, rows c4..c4+3 -> one uint32 out
#pragma unroll
    for (int p = 0; p < 4; ++p) {
        int c = rr + p * 16;
        uint32_t o = 0;
#pragma unroll
        for (int j = 0; j < 4; ++j) {
            uint32_t b = (t[c4 + j][c >> 2] >> ((c & 3) * 8)) & 0xffu;
            o |= b << (j * 8);
        }
        wt[((size_t)(n0 + c) * KDIM + k0 + c4) >> 2] = o;
    }
}

// ---------- i8 GEMM: C = A * Bt^T + bias; BM=128 x BN=256, 512 thr, R0 sync structure ----------
// Best measured config (R7: gemm 48.0 us, MfmaUtil 28, FETCH 24.7 MB, 0 conflicts).
// launch_bounds(512,4): 128-VGPR cap (unified VGPR+AGPR file!) -> no spill, 2 blocks/CU.
// R6's (512,6) capped regs at ~85 < acc's 64+overhead -> 1 GB scratch spill. Never again.
// R8 (256^2, 16 waves/block, ops/byte 256) regressed to 49.4: per-block barrier lockstep
// cost beats staging savings past 8 waves/block. 128x256 @ 8 waves is the family optimum.
// Staged bytes/MFMA: 192 B (vs 256 B at 128^2). LDS row = 64B = 4 x 16B chunks;
// chunk c of row r stored at c ^ ((r>>1)&3) (verified SQ_LDS_BANK_CONFLICT == 0).
__global__ __launch_bounds__(512, 4)
void gemm_i8_kernel(const int8_t* __restrict__ A,   // [M][K] int8
                    const int8_t* __restrict__ Bt,  // [N][K] int8
                    const float* __restrict__ bias, // [N]
                    float* __restrict__ C) {        // [M][N] fp32
    __shared__ alignas(16) int8_t lA[2][BM * BK];   // 2 x 8 KB
    __shared__ alignas(16) int8_t lB[2][BN * BK];   // 2 x 16 KB

    const int tid  = threadIdx.x;
    const int lane = tid & 63;
    const int wave = tid >> 6;           // 0..7
    const int wm   = wave & 1;           // M-half: 64 rows
    const int wn   = wave >> 1;          // N-quarter: 64 cols

    // XCD-aware bijective swizzle: 512 blocks -> 64 per XCD = 8 m-panels x 8 n-panels,
    // n fastest so A-panels are shared by consecutive co-resident blocks on one XCD.
    const int bidlin = blockIdx.y * gridDim.x + blockIdx.x;   // 0..511
    const int xcd    = bidlin & 7;
    const int idx    = bidlin >> 3;                            // 0..63
    const int m0     = (xcd * 8 + (idx >> 3)) * BM;            // 64 m-panels
    const int n0     = (idx & 7) * BN;                         // 8 n-panels

    // staging: A wave covers rows [wave*16,+16) (1 issue); B wave covers [wave*32,+32) (2 issues)
    const int srow = lane >> 2;                       // 0..15
    const int schk = (lane & 3) ^ ((srow >> 1) & 3);  // swizzled source chunk
    const int8_t* gA = A  + (size_t)(m0 + wave * 16 + srow) * KDIM + schk * 16;
    const int8_t* gB = Bt + (size_t)(n0 + wave * 32 + srow) * KDIM + schk * 16;
    const int lwoA = wave * 1024;
    const int lwoB = wave * 2048;

    // fragments: lane reads row (.. + lr), global chunk quad -> LDS chunk quad^((lr>>1)&3)
    const int quad = lane >> 4;
    const int lr   = lane & 15;
    const int fchk = (quad ^ ((lr >> 1) & 3)) * 16;
    const int aoff = (wm * 64 + lr) * BK + fchk;
    const int boff = (wn * 64 + lr) * BK + fchk;

    v4i acc[4][4];
#pragma unroll
    for (int i = 0; i < 4; ++i)
#pragma unroll
        for (int j = 0; j < 4; ++j)
            acc[i][j] = (v4i){0, 0, 0, 0};

#define STAGE(buf, kof)                                                        \
    do {                                                                       \
        async_ld16(gA + (kof), &lA[buf][lwoA]);                                \
        async_ld16(gB + (kof), &lB[buf][lwoB]);                                \
        async_ld16(gB + (kof) + (size_t)16 * KDIM, &lB[buf][lwoB + 1024]);     \
    } while (0)

#define COMPUTE(buf)                                                           \
    do {                                                                       \
        v4i af[4], bf[4];                                                      \
        _Pragma("unroll")                                                      \
        for (int i = 0; i < 4; ++i)                                            \
            af[i] = *(const v4i*)&lA[buf][aoff + i * 1024];                    \
        _Pragma("unroll")                                                      \
        for (int j = 0; j < 4; ++j)                                            \
            bf[j] = *(const v4i*)&lB[buf][boff + j * 1024];                    \
        _Pragma("unroll")                                                      \
        for (int i = 0; i < 4; ++i)                                            \
            _Pragma("unroll")                                                  \
            for (int j = 0; j < 4; ++j)                                        \
                acc[i][j] = __builtin_amdgcn_mfma_i32_16x16x64_i8(             \
                    af[i], bf[j], acc[i][j], 0, 0, 0);                         \
    } while (0)

    STAGE(0, 0);
    int kof = BK;
    for (int it = 0; it < KDIM / BK - 1; ++it) {
        __syncthreads();                 // drains vmcnt: tile `it` visible; buf (it+1)&1 free
        STAGE((it + 1) & 1, kof);        // prefetch next tile (flies during compute)
        kof += BK;
        COMPUTE(it & 1);
    }
    __syncthreads();
    COMPUTE((KDIM / BK - 1) & 1);

    // epilogue: C/D layout col = lane&15, row = quad*4 + reg (verified, dtype-indep)
    const int crow = m0 + wm * 64 + quad * 4;
    const int ccol = n0 + wn * 64 + lr;
    float bj[4];
#pragma unroll
    for (int j = 0; j < 4; ++j) bj[j] = bias[ccol + j * 16];
#pragma unroll
    for (int i = 0; i < 4; ++i)
#pragma unroll
        for (int j = 0; j < 4; ++j)
#pragma unroll
            for (int r = 0; r < 4; ++r)
                C[(size_t)(crow + i * 16 + r) * NDIM + (ccol + j * 16)] = (float)acc[i][j][r] + bj[j];
}

extern "C" void kernel_launch(void* const* d_in, const int* in_sizes, int n_in,
                              void* d_out, int out_size, void* d_ws, size_t ws_size,
                              hipStream_t stream) {
    const float* x    = (const float*)d_in[0];   // [8192, 2048] fp32
    const float* w    = (const float*)d_in[1];   // [2048, 2048] fp32 (integer-valued)
    const float* xs   = (const float*)d_in[2];   // scalar
    const float* bias = (const float*)d_in[3];   // [2048]
    float* out = (float*)d_out;                  // [8192, 2048] fp32

    int8_t* xq = (int8_t*)d_ws;                          // 16 MB
    int8_t* wt = xq + (size_t)MDIM * KDIM;               //  4 MB

    quant_kernel<<<WBLOCKS + XBLOCKS, 256, 0, stream>>>(
        (const float4*)x, (uint32_t*)xq, xs, w, (uint32_t*)wt);
    gemm_i8_kernel<<<dim3(NDIM / BN, MDIM / BM), 512, 0, stream>>>(xq, wt, bias, out);
}